// Round 1
// baseline (471.224 us; speedup 1.0000x reference)
//
#include <hip/hip_runtime.h>
#include <cstddef>

#define BATCH 4
#define SEQ   4096
#define DIM   2048
#define EPSF  1e-5f
#define TCHUNK 8
#define CPB   (SEQ / TCHUNK)         // 512 chunks per batch
#define NBLK  (BATCH * CPB)          // 2048 blocks

#define AGGF 0x40000000u
#define INCF 0x80000000u
#define VALM 0xFFFFu

__device__ __forceinline__ float wave_sum(float v) {
#pragma unroll
    for (int off = 32; off > 0; off >>= 1)
        v += __shfl_down(v, off, 64);
    return v;
}
__device__ __forceinline__ int wave_sum_i(int v) {
#pragma unroll
    for (int off = 32; off > 0; off >>= 1)
        v += __shfl_down(v, off, 64);
    return v;
}

// Single-pass fused kernel: rmsnorm -> causal dwconv(W=4) -> silu -> sign of
// (p1-p0) dot  ==> mask bits, then ticket-ordered decoupled-lookback scan over
// chunks (per-batch chain), then selected rows written DIRECTLY from the
// registers that already hold x — eliminating scatter's x re-read and the
// separate scan dispatch.
//
// Deadlock-freedom: chunk id comes from a global atomic ticket, so any block
// waiting on chunk c' < c knows c' was acquired by an earlier, already-running
// block; aggregates are published before any spin. Lookback is wave-parallel
// (64 predecessors per hop), so depth-511 chains resolve in <= 8 hops.
//
// ws layout (u32): [0] ticket, [1..5) nsel per batch, [8..8+2048) chain.
__global__ __launch_bounds__(256, 2) void fused_kernel(
    const float* __restrict__ x, const float* __restrict__ nw,
    const float* __restrict__ cw, const float* __restrict__ pw,
    unsigned int* __restrict__ ws, float* __restrict__ out)
{
    __shared__ float lds_ss[11][4];    // 3 warmup + 8 main rows, per wave
    __shared__ float lds_acc[8][4];
    __shared__ unsigned int lds_chunk;
    __shared__ unsigned int lds_excl;

    unsigned int* ticket = ws;
    unsigned int* nsel   = ws + 1;
    unsigned int* chain  = ws + 8;

    const int t = threadIdx.x, lane = t & 63, wid = t >> 6;

    if (t == 0) lds_chunk = atomicAdd(ticket, 1u);

    // weight prep overlaps the ticket round-trip
    const int d0 = 4 * t, d1 = d0 + 1024;
    float cwn[8][4], pd[8];
    {
        float4 n0 = *(const float4*)(nw + d0);
        float4 n1 = *(const float4*)(nw + d1);
        float nv[8] = {n0.x, n0.y, n0.z, n0.w, n1.x, n1.y, n1.z, n1.w};
#pragma unroll
        for (int i = 0; i < 8; ++i) {
            const int d = (i < 4) ? (d0 + i) : (d1 + i - 4);
            float4 c4 = *(const float4*)(cw + 4 * d);
            cwn[i][0] = c4.x * nv[i]; cwn[i][1] = c4.y * nv[i];
            cwn[i][2] = c4.z * nv[i]; cwn[i][3] = c4.w * nv[i];
        }
        float4 a0 = *(const float4*)(pw + d0);
        float4 a1 = *(const float4*)(pw + d1);
        float4 b0 = *(const float4*)(pw + DIM + d0);
        float4 b1 = *(const float4*)(pw + DIM + d1);
        pd[0] = b0.x - a0.x; pd[1] = b0.y - a0.y; pd[2] = b0.z - a0.z; pd[3] = b0.w - a0.w;
        pd[4] = b1.x - a1.x; pd[5] = b1.y - a1.y; pd[6] = b1.z - a1.z; pd[7] = b1.w - a1.w;
    }
    __syncthreads();                       // barrier 0: ticket visible
    const unsigned chunk = lds_chunk;
    const int b    = (int)(chunk >> 9);    // / CPB
    const int cidx = (int)(chunk & (CPB - 1));
    const int s0   = cidx * TCHUNK;
    const float* xb = x + (size_t)b * SEQ * DIM;

    // ---- bulk-issue all 11 row loads (3 warmup + 8 main) ----
    float wv[3][8];
#pragma unroll
    for (int w = 0; w < 3; ++w) {
        const int s = s0 - 3 + w;
        if (s >= 0) {
            float4 a = *(const float4*)(xb + (size_t)s * DIM + d0);
            float4 c = *(const float4*)(xb + (size_t)s * DIM + d1);
            wv[w][0]=a.x; wv[w][1]=a.y; wv[w][2]=a.z; wv[w][3]=a.w;
            wv[w][4]=c.x; wv[w][5]=c.y; wv[w][6]=c.z; wv[w][7]=c.w;
        } else {
#pragma unroll
            for (int i = 0; i < 8; ++i) wv[w][i] = 0.f;
        }
    }
    float xv[8][8];
#pragma unroll
    for (int j = 0; j < 8; ++j) {
        const int s = s0 + j;
        float4 a = *(const float4*)(xb + (size_t)s * DIM + d0);
        float4 c = *(const float4*)(xb + (size_t)s * DIM + d1);
        xv[j][0]=a.x; xv[j][1]=a.y; xv[j][2]=a.z; xv[j][3]=a.w;
        xv[j][4]=c.x; xv[j][5]=c.y; xv[j][6]=c.z; xv[j][7]=c.w;
    }

    // ---- sum-of-squares for all 11 rows, one barrier ----
#pragma unroll
    for (int w = 0; w < 3; ++w) {
        float ss = 0.f;
#pragma unroll
        for (int i = 0; i < 8; ++i) ss += wv[w][i] * wv[w][i];
        ss = wave_sum(ss);
        if (lane == 0) lds_ss[w][wid] = ss;
    }
#pragma unroll
    for (int j = 0; j < 8; ++j) {
        float ss = 0.f;
#pragma unroll
        for (int i = 0; i < 8; ++i) ss += xv[j][i] * xv[j][i];
        ss = wave_sum(ss);
        if (lane == 0) lds_ss[3 + j][wid] = ss;
    }
    __syncthreads();                       // barrier 1

    float h1[8], h2[8], h3[8];
#pragma unroll
    for (int w = 0; w < 3; ++w) {
        const float sum4 = lds_ss[w][0] + lds_ss[w][1]
                         + lds_ss[w][2] + lds_ss[w][3];
        const float rstd = 1.0f / sqrtf(sum4 * (1.0f / DIM) + EPSF);
        float* h = (w == 0) ? h3 : (w == 1) ? h2 : h1;
#pragma unroll
        for (int i = 0; i < 8; ++i) h[i] = wv[w][i] * rstd;
    }

#pragma unroll
    for (int j = 0; j < 8; ++j) {
        const float sum4 = lds_ss[3 + j][0] + lds_ss[3 + j][1]
                         + lds_ss[3 + j][2] + lds_ss[3 + j][3];
        const float rstd = 1.0f / sqrtf(sum4 * (1.0f / DIM) + EPSF);
        float acc = 0.f;
#pragma unroll
        for (int i = 0; i < 8; ++i) {
            const float hc = xv[j][i] * rstd;
            const float y = cwn[i][0] * h3[i] + cwn[i][1] * h2[i]
                          + cwn[i][2] * h1[i] + cwn[i][3] * hc;
            const float sig = 1.0f / (1.0f + __expf(-y));
            acc += (y * sig) * pd[i];
            h3[i] = h2[i]; h2[i] = h1[i]; h1[i] = hc;
        }
        acc = wave_sum(acc);
        if (lane == 0) lds_acc[j][wid] = acc;
    }
    __syncthreads();                       // barrier 2

    // ---- mask bits (deterministic same result on every thread) ----
    unsigned mbits = 0; int cnt = 0;
#pragma unroll
    for (int j = 0; j < 8; ++j) {
        const float a = lds_acc[j][0] + lds_acc[j][1]
                      + lds_acc[j][2] + lds_acc[j][3];
        if (a > 0.f) { mbits |= (1u << j); ++cnt; }
    }

    // ---- publish aggregate, lookback, publish inclusive ----
    if (cidx == 0) {
        if (t == 0) {
            lds_excl = 0;
            __hip_atomic_store(&chain[chunk], (unsigned)cnt | INCF,
                               __ATOMIC_RELEASE, __HIP_MEMORY_SCOPE_AGENT);
        }
    } else {
        if (t == 0)
            __hip_atomic_store(&chain[chunk], (unsigned)cnt | AGGF,
                               __ATOMIC_RELEASE, __HIP_MEMORY_SCOPE_AGENT);
        if (wid == 0) {
            int excl = 0;
            int back = cidx;
            const unsigned int* chb = chain + ((size_t)b << 9);
            while (back > 0) {
                const int look = back - 1 - lane;   // lane 0 = nearest pred
                unsigned v = 0;
                if (look >= 0) {
                    do {
                        v = __hip_atomic_load(chb + look, __ATOMIC_ACQUIRE,
                                              __HIP_MEMORY_SCOPE_AGENT);
                    } while (!(v & (AGGF | INCF)));
                }
                const unsigned long long bal = __ballot((v & INCF) != 0);
                const int val = (int)(v & VALM);
                if (bal) {
                    const int k = (int)__ffsll((unsigned long long)bal) - 1;
                    excl += wave_sum_i((lane <= k) ? val : 0);
                    back = 0;
                } else {
                    excl += wave_sum_i((look >= 0) ? val : 0);
                    back -= 64;
                }
            }
            if (lane == 0) {
                lds_excl = (unsigned)excl;
                __hip_atomic_store(&chain[chunk], (unsigned)(excl + cnt) | INCF,
                                   __ATOMIC_RELEASE, __HIP_MEMORY_SCOPE_AGENT);
                if (cidx == CPB - 1) nsel[b] = (unsigned)(excl + cnt);
            }
        }
    }
    __syncthreads();                       // barrier 3

    // ---- write selected rows straight from registers ----
    if (mbits) {
        int dest = (int)lds_excl;
#pragma unroll
        for (int j = 0; j < 8; ++j) {
            if (mbits & (1u << j)) {
                float* o = out + ((size_t)b * SEQ + dest) * DIM;
                float4 a = {xv[j][0], xv[j][1], xv[j][2], xv[j][3]};
                float4 c = {xv[j][4], xv[j][5], xv[j][6], xv[j][7]};
                *(float4*)(o + d0) = a;
                *(float4*)(o + d1) = c;
                ++dest;
            }
        }
    }
}

// Zero-fill pass: output rows [nsel, S) are all zeros. Branches are uniform
// per block; fully-selected blocks exit after one hot scalar load.
__global__ __launch_bounds__(256) void zeros_kernel(
    const unsigned int* __restrict__ ws, float* __restrict__ out)
{
    const int bpb = SEQ / 8;                       // 512 blocks per batch
    const int b   = blockIdx.x / bpb;
    const int r0  = (blockIdx.x % bpb) * 8;
    const int n   = (int)ws[1 + b];
    if (r0 + 8 <= n) return;
    const int t = threadIdx.x;
    const float4 z = make_float4(0.f, 0.f, 0.f, 0.f);
    float* ob = out + (size_t)b * SEQ * DIM;
#pragma unroll
    for (int j = 0; j < 8; ++j) {
        const int r = r0 + j;
        if (r >= n) {
            float* o = ob + (size_t)r * DIM;
            *(float4*)(o + 4 * t)        = z;
            *(float4*)(o + 4 * t + 1024) = z;
        }
    }
}

extern "C" void kernel_launch(void* const* d_in, const int* in_sizes, int n_in,
                              void* d_out, int out_size, void* d_ws, size_t ws_size,
                              hipStream_t stream) {
    const float* x  = (const float*)d_in[0];   // [B,S,D]
    const float* nw = (const float*)d_in[1];   // [D]
    const float* cw = (const float*)d_in[2];   // [D,4]
    const float* pw = (const float*)d_in[3];   // [2,D]
    float* out = (float*)d_out;                // [B,S,D]

    unsigned int* ws = (unsigned int*)d_ws;    // ticket + nsel[4] + chain[2048]

    hipMemsetAsync(d_ws, 0, (8 + NBLK) * sizeof(unsigned int), stream);
    fused_kernel<<<NBLK, 256, 0, stream>>>(x, nw, cw, pw, ws, out);
    zeros_kernel<<<BATCH * (SEQ / 8), 256, 0, stream>>>(ws, out);
}

// Round 3
// 263.437 us; speedup vs baseline: 1.7888x; 1.7888x over previous
//
#include <hip/hip_runtime.h>
#include <cstddef>

#define BATCH 4
#define SEQ   4096
#define DIM   2048
#define EPSF  1e-5f
#define TCHUNK 8
#define CPB   (SEQ / TCHUNK)         // 512 chunks per batch
#define NBLK  (BATCH * CPB)          // 2048 blocks

__device__ __forceinline__ float wave_sum(float v) {
#pragma unroll
    for (int off = 32; off > 0; off >>= 1)
        v += __shfl_down(v, off, 64);
    return v;
}
__device__ __forceinline__ int wave_sum_i(int v) {
#pragma unroll
    for (int off = 32; off > 0; off >>= 1)
        v += __shfl_down(v, off, 64);
    return v;
}

// Phase 1: fused rmsnorm -> causal depthwise conv(W=4) -> silu -> (p1-p0) dot
// -> sign. Identical arithmetic to the proven round-0 kernel (265us version).
// One block owns all D=2048 (256 thr x 8 ch), slides over TCHUNK=8 tokens.
// Blocks are fully independent (no inter-block coupling -- the round-1
// lookback experiment showed coupling costs ~150us in generation
// serialization). Output: ONE packed u32 per chunk:
//   cnt[chunk] = count(4b used of low16) | (mask_bits << 16)
// 8 KB total -- the separate scan dispatch is gone; scatter blocks rebuild
// prefixes themselves from these counts.
__global__ __launch_bounds__(256, 3) void mask_kernel(
    const float* __restrict__ x, const float* __restrict__ nw,
    const float* __restrict__ cw, const float* __restrict__ pw,
    unsigned int* __restrict__ cnt)
{
    __shared__ float lds_ss[3][4][4];   // [group(2=warmup)][tok-in-group][wave]
    __shared__ float lds_acc[2][4][4];  // write-once slots -> no WAR hazards

    const int t = threadIdx.x, lane = t & 63, wid = t >> 6;
    // XCD swizzle: seq-adjacent chunks -> same XCD (L2 reuse of warm-up rows)
    const int G = gridDim.x;
    const int chunk = (blockIdx.x & 7) * (G >> 3) + (blockIdx.x >> 3);
    const int b  = chunk / CPB;
    const int s0 = (chunk % CPB) * TCHUNK;
    const int d0 = 4 * t, d1 = d0 + 1024;

    // conv*norm folded (cwn), projection diff (pd)
    float cwn[8][4], pd[8];
    {
        float4 n0 = *(const float4*)(nw + d0);
        float4 n1 = *(const float4*)(nw + d1);
        float nv[8] = {n0.x, n0.y, n0.z, n0.w, n1.x, n1.y, n1.z, n1.w};
#pragma unroll
        for (int i = 0; i < 8; ++i) {
            const int d = (i < 4) ? (d0 + i) : (d1 + i - 4);
            float4 c4 = *(const float4*)(cw + 4 * d);
            cwn[i][0] = c4.x * nv[i]; cwn[i][1] = c4.y * nv[i];
            cwn[i][2] = c4.z * nv[i]; cwn[i][3] = c4.w * nv[i];
        }
        float4 a0 = *(const float4*)(pw + d0);
        float4 a1 = *(const float4*)(pw + d1);
        float4 b0 = *(const float4*)(pw + DIM + d0);
        float4 b1 = *(const float4*)(pw + DIM + d1);
        pd[0] = b0.x - a0.x; pd[1] = b0.y - a0.y; pd[2] = b0.z - a0.z; pd[3] = b0.w - a0.w;
        pd[4] = b1.x - a1.x; pd[5] = b1.y - a1.y; pd[6] = b1.z - a1.z; pd[7] = b1.w - a1.w;
    }

    const float* xb = x + (size_t)b * SEQ * DIM;
    float h1[8], h2[8], h3[8];   // normalized rows s-1, s-2, s-3

    // ---- warm-up: tokens s0-3..s0-1 (1 barrier) ----
    {
        float wv[3][8];
#pragma unroll
        for (int w = 0; w < 3; ++w) {
            const int s = s0 - 3 + w;
            if (s >= 0) {
                float4 a = *(const float4*)(xb + (size_t)s * DIM + d0);
                float4 c = *(const float4*)(xb + (size_t)s * DIM + d1);
                wv[w][0]=a.x; wv[w][1]=a.y; wv[w][2]=a.z; wv[w][3]=a.w;
                wv[w][4]=c.x; wv[w][5]=c.y; wv[w][6]=c.z; wv[w][7]=c.w;
            } else {
#pragma unroll
                for (int i = 0; i < 8; ++i) wv[w][i] = 0.f;
            }
            float ss = 0.f;
#pragma unroll
            for (int i = 0; i < 8; ++i) ss += wv[w][i] * wv[w][i];
            ss = wave_sum(ss);
            if (lane == 0) lds_ss[2][w][wid] = ss;
        }
        __syncthreads();
#pragma unroll
        for (int w = 0; w < 3; ++w) {
            const float sum4 = lds_ss[2][w][0] + lds_ss[2][w][1]
                             + lds_ss[2][w][2] + lds_ss[2][w][3];
            const float rstd = 1.0f / sqrtf(sum4 * (1.0f / DIM) + EPSF);
            float* h = (w == 0) ? h3 : (w == 1) ? h2 : h1;
#pragma unroll
            for (int i = 0; i < 8; ++i) h[i] = wv[w][i] * rstd;
        }
    }

    // ---- main: 2 groups of 4 tokens, 1 barrier each + 1 final ----
#pragma unroll
    for (int g = 0; g < 2; ++g) {
        float xv[4][8];
#pragma unroll
        for (int j = 0; j < 4; ++j) {
            const int s = s0 + 4 * g + j;
            float4 a = *(const float4*)(xb + (size_t)s * DIM + d0);
            float4 c = *(const float4*)(xb + (size_t)s * DIM + d1);
            xv[j][0]=a.x; xv[j][1]=a.y; xv[j][2]=a.z; xv[j][3]=a.w;
            xv[j][4]=c.x; xv[j][5]=c.y; xv[j][6]=c.z; xv[j][7]=c.w;
        }
#pragma unroll
        for (int j = 0; j < 4; ++j) {
            float ss = 0.f;
#pragma unroll
            for (int i = 0; i < 8; ++i) ss += xv[j][i] * xv[j][i];
            ss = wave_sum(ss);
            if (lane == 0) lds_ss[g][j][wid] = ss;
        }
        __syncthreads();   // orders this group's ss writes (+ prev acc writes)
#pragma unroll
        for (int j = 0; j < 4; ++j) {
            const float sum4 = lds_ss[g][j][0] + lds_ss[g][j][1]
                             + lds_ss[g][j][2] + lds_ss[g][j][3];
            const float rstd = 1.0f / sqrtf(sum4 * (1.0f / DIM) + EPSF);
            float acc = 0.f;
#pragma unroll
            for (int i = 0; i < 8; ++i) {
                const float hc = xv[j][i] * rstd;
                const float y = cwn[i][0] * h3[i] + cwn[i][1] * h2[i]
                              + cwn[i][2] * h1[i] + cwn[i][3] * hc;
                const float sig = 1.0f / (1.0f + __expf(-y));
                acc += (y * sig) * pd[i];
                h3[i] = h2[i]; h2[i] = h1[i]; h1[i] = hc;
            }
            acc = wave_sum(acc);
            if (lane == 0) lds_acc[g][j][wid] = acc;
        }
    }
    __syncthreads();   // final: both groups' acc slots visible

    // ---- pack 8 signs + count into one u32 (wave 0 only) ----
    if (wid == 0) {
        int sel = 0;
        if (lane < 8) {
            const int g = lane >> 2, j = lane & 3;
            const float a = lds_acc[g][j][0] + lds_acc[g][j][1]
                          + lds_acc[g][j][2] + lds_acc[g][j][3];
            sel = (a > 0.f) ? 1 : 0;   // lane = token offset (g*4+j)
        }
        const unsigned long long bal = __ballot(sel);
        if (lane == 0)
            cnt[chunk] = (unsigned)__popcll(bal) | ((unsigned)(bal & 0xFFull) << 16);
    }
}

// Phase 2 (scan+scatter fused): one block per 8-row chunk. Each block
// independently rebuilds its exclusive prefix + batch total by reducing the
// 512 per-batch chunk counts (2 KB, L2-hot; packed reduce gives both at
// once). x loads for selected rows are issued BEFORE the reduce -- their
// addresses depend only on `bits` (one uniform scalar load) -- so HBM/L3
// latency hides under the reduction. Bijection onto [0,S): selected row ->
// p-1, unselected -> nsel + s - p.
__global__ __launch_bounds__(256) void scatter_kernel(
    const float* __restrict__ x, const unsigned int* __restrict__ cnt,
    float* __restrict__ out)
{
    __shared__ unsigned int lds_r[4];
    const int blk  = blockIdx.x;
    const int b    = blk >> 9;            // / CPB
    const int cidx = blk & (CPB - 1);
    const int t = threadIdx.x, lane = t & 63, wid = t >> 6;

    const unsigned int* cb = cnt + b * CPB;
    const unsigned vown = cb[cidx];            // uniform -> scalar load
    const unsigned bits = vown >> 16;

    // issue count loads (for the reduce) ...
    const unsigned u0 = cb[t];
    const unsigned u1 = cb[256 + t];

    // ... and the selected x rows, before the reduce completes
    const int s0 = cidx * TCHUNK;
    const float* xb = x + (size_t)b * SEQ * DIM;
    const int d0 = 4 * t, d1 = d0 + 1024;
    const float4 z = make_float4(0.f, 0.f, 0.f, 0.f);
    float4 ra[TCHUNK], rc[TCHUNK];
#pragma unroll
    for (int j = 0; j < TCHUNK; ++j) {
        if ((bits >> j) & 1) {                 // uniform branch
            const float* src = xb + (size_t)(s0 + j) * DIM;
            ra[j] = *(const float4*)(src + d0);
            rc[j] = *(const float4*)(src + d1);
        } else { ra[j] = z; rc[j] = z; }
    }

    // packed reduce: low16 = exclusive prefix contribution, high16 = total
    const int c0 = (int)(u0 & 0xFFFFu), c1 = (int)(u1 & 0xFFFFu);
    int pack = (((t < cidx) ? c0 : 0) + ((256 + t < cidx) ? c1 : 0))
             + ((c0 + c1) << 16);
    pack = wave_sum_i(pack);
    if (lane == 0) lds_r[wid] = (unsigned)pack;
    __syncthreads();
    const unsigned tot = lds_r[0] + lds_r[1] + lds_r[2] + lds_r[3];
    const int pre  = (int)(tot & 0xFFFFu);
    const int nsel = (int)(tot >> 16);

    float* ob = out + (size_t)b * SEQ * DIM;
#pragma unroll
    for (int j = 0; j < TCHUNK; ++j) {
        const int incl = __popc(bits & ((2u << j) - 1u));   // inclusive in-chunk
        const int p    = pre + incl;
        const int sel  = (bits >> j) & 1;
        const int dest = sel ? (p - 1) : (nsel + s0 + j - p);
        float* o = ob + (size_t)dest * DIM;
        *(float4*)(o + d0) = ra[j];
        *(float4*)(o + d1) = rc[j];
    }
}

extern "C" void kernel_launch(void* const* d_in, const int* in_sizes, int n_in,
                              void* d_out, int out_size, void* d_ws, size_t ws_size,
                              hipStream_t stream) {
    const float* x  = (const float*)d_in[0];   // [B,S,D]
    const float* nw = (const float*)d_in[1];   // [D]
    const float* cw = (const float*)d_in[2];   // [D,4]
    const float* pw = (const float*)d_in[3];   // [2,D]
    float* out = (float*)d_out;                // [B,S,D]

    unsigned int* cnt = (unsigned int*)d_ws;   // NBLK u32 = 8 KB; every entry
                                               // written by mask before scatter
                                               // reads -> no memset needed
    mask_kernel<<<NBLK, 256, 0, stream>>>(x, nw, cw, pw, cnt);
    scatter_kernel<<<NBLK, 256, 0, stream>>>(x, cnt, out);
}